// Round 1
// baseline (1258.868 us; speedup 1.0000x reference)
//
#include <hip/hip_runtime.h>

#define NN   20000
#define EE   640000
#define ET   (EE + NN)
#define TXTK 768
#define MELK 6400
#define HIDC 128

typedef float  float4_ __attribute__((ext_vector_type(4)));
typedef short  short4_ __attribute__((ext_vector_type(4)));
typedef short  short8_ __attribute__((ext_vector_type(8)));
typedef __bf16 bf16x8  __attribute__((ext_vector_type(8)));

__device__ __forceinline__ unsigned short bf_hi_trunc(float f) {
  return (unsigned short)(__float_as_uint(f) >> 16);
}
__device__ __forceinline__ float bf_to_f(unsigned short s) {
  return __uint_as_float(((unsigned)s) << 16);
}
__device__ __forceinline__ unsigned short bf_rne(float f) {
  unsigned u = __float_as_uint(f);
  u += 0x7FFFu + ((u >> 16) & 1u);
  return (unsigned short)(u >> 16);
}

// ---------------- weight prep: fp32 [K,N] -> bf16 hi/lo transposed [N,K] ----
__global__ __launch_bounds__(256) void k_prep_w(const float* __restrict__ W, int K, int N,
                                                short* __restrict__ hi, short* __restrict__ lo) {
  int t = blockIdx.x * 256 + threadIdx.x;
  if (t >= K * N) return;
  int k = t / N, n = t - k * N;
  float f = W[t];
  unsigned short h = bf_hi_trunc(f);
  unsigned short l = bf_rne(f - bf_to_f(h));
  hi[(long)n * K + k] = (short)h;
  lo[(long)n * K + k] = (short)l;
}

// ---------------- split-bf16 MFMA GEMM:  C = act(A @ W + b) ------------------
// A row = [A1 row (K1) | A2 row (K2)], fp32, converted to hi/lo on the fly.
// W pre-split/transposed: Bhi/Blo are [Ntot, Ktot] (col-major wrt original).
// Tile: 128 rows x 128 cols per block (blockIdx.y = col block), K-step 32.
__global__ __launch_bounds__(256) void k_gemm(
    const float* __restrict__ A1, int K1, const float* __restrict__ A2, int K2,
    const short* __restrict__ Bhi, const short* __restrict__ Blo, int Ktot,
    const float* __restrict__ bias, int act,
    float* __restrict__ C, int ldC, int M) {
  __shared__ short lAhi[128 * 40], lAlo[128 * 40], lBhi[128 * 40], lBlo[128 * 40];
  int t = threadIdx.x;
  int lane = t & 63, wv = t >> 6;
  int m16 = lane & 15, q = lane >> 4;
  int bm = blockIdx.x;
  int col0 = blockIdx.y * 128;

  float4_ acc[8][2];
#pragma unroll
  for (int rt = 0; rt < 8; ++rt)
#pragma unroll
    for (int ct = 0; ct < 2; ++ct) acc[rt][ct] = (float4_){0.f, 0.f, 0.f, 0.f};

  for (int ks = 0; ks < Ktot; ks += 32) {
    __syncthreads();
    // stage A tile 128x32 fp32 -> hi/lo bf16
#pragma unroll
    for (int j = 0; j < 4; ++j) {
      int f = t + j * 256;
      int row = f >> 3, c4 = f & 7;
      int col = ks + c4 * 4;
      long rg = (long)bm * 128 + row;
      if (rg >= M) rg = M - 1;
      const float* sp = (col < K1) ? (A1 + rg * K1 + col) : (A2 + rg * K2 + (col - K1));
      float4_ v = *(const float4_*)sp;
      short4_ h, l;
#pragma unroll
      for (int c = 0; c < 4; ++c) {
        unsigned short hh = bf_hi_trunc(v[c]);
        h[c] = (short)hh;
        l[c] = (short)bf_rne(v[c] - bf_to_f(hh));
      }
      *(short4_*)&lAhi[row * 40 + c4 * 4] = h;
      *(short4_*)&lAlo[row * 40 + c4 * 4] = l;
    }
    // stage W tiles 128(col) x 32(k), already bf16, transposed layout
#pragma unroll
    for (int j = 0; j < 2; ++j) {
      int f = t + j * 256;
      int col = f >> 2, k8 = f & 3;
      long go = (long)(col0 + col) * Ktot + ks + k8 * 8;
      *(short8_*)&lBhi[col * 40 + k8 * 8] = *(const short8_*)(Bhi + go);
      *(short8_*)&lBlo[col * 40 + k8 * 8] = *(const short8_*)(Blo + go);
    }
    __syncthreads();

    bf16x8 bh[2], bl[2];
#pragma unroll
    for (int ct = 0; ct < 2; ++ct) {
      int cb = (wv * 32 + ct * 16 + m16) * 40 + q * 8;
      bh[ct] = *(const bf16x8*)&lBhi[cb];
      bl[ct] = *(const bf16x8*)&lBlo[cb];
    }
#pragma unroll
    for (int rt = 0; rt < 8; ++rt) {
      int ab = (rt * 16 + m16) * 40 + q * 8;
      bf16x8 ah = *(const bf16x8*)&lAhi[ab];
      bf16x8 al = *(const bf16x8*)&lAlo[ab];
#pragma unroll
      for (int ct = 0; ct < 2; ++ct) {
        acc[rt][ct] = __builtin_amdgcn_mfma_f32_16x16x32_bf16(ah, bh[ct], acc[rt][ct], 0, 0, 0);
        acc[rt][ct] = __builtin_amdgcn_mfma_f32_16x16x32_bf16(ah, bl[ct], acc[rt][ct], 0, 0, 0);
        acc[rt][ct] = __builtin_amdgcn_mfma_f32_16x16x32_bf16(al, bh[ct], acc[rt][ct], 0, 0, 0);
      }
    }
  }
  // epilogue: C layout col=lane&15, row=q*4+reg
#pragma unroll
  for (int rt = 0; rt < 8; ++rt) {
#pragma unroll
    for (int ct = 0; ct < 2; ++ct) {
      int colg = col0 + wv * 32 + ct * 16 + m16;
      float b = bias ? bias[colg] : 0.0f;
#pragma unroll
      for (int r = 0; r < 4; ++r) {
        int rowg = bm * 128 + rt * 16 + q * 4 + r;
        if (rowg < M) {
          float v = acc[rt][ct][r] + b;
          if (act == 1) v = fmaxf(v, 0.0f);
          else if (act == 2) v = (v > 0.0f) ? v : expm1f(v);
          C[(long)rowg * ldC + colg] = v;
        }
      }
    }
  }
}

// ---------------- CSR build ------------------------------------------------
__global__ __launch_bounds__(256) void k_count(const int* __restrict__ ei, int* __restrict__ cnt) {
  int i = blockIdx.x * 256 + threadIdx.x;
  if (i >= ET) return;
  int dst = (i < EE) ? ei[EE + i] : (i - EE);
  atomicAdd(&cnt[dst], 1);
}

__global__ __launch_bounds__(1024) void k_scan(const int* __restrict__ cnt, int* __restrict__ rs, int n) {
  __shared__ int sm[1024];
  __shared__ int carry;
  int tid = threadIdx.x;
  if (tid == 0) { carry = 0; rs[0] = 0; }
  __syncthreads();
  int nch = (n + 1023) >> 10;
  for (int c = 0; c < nch; ++c) {
    int i = (c << 10) + tid;
    int v = (i < n) ? cnt[i] : 0;
    sm[tid] = v;
    __syncthreads();
    for (int off = 1; off < 1024; off <<= 1) {
      int tv = (tid >= off) ? sm[tid - off] : 0;
      __syncthreads();
      sm[tid] += tv;
      __syncthreads();
    }
    int incl = sm[tid];
    int total = sm[1023];
    int base = carry;
    if (i < n) rs[i + 1] = base + incl;
    __syncthreads();
    if (tid == 0) carry = base + total;
    __syncthreads();
  }
}

__global__ __launch_bounds__(256) void k_fill(const int* __restrict__ ei, const int* __restrict__ rs,
                                              int* __restrict__ cur, int* __restrict__ csr) {
  int i = blockIdx.x * 256 + threadIdx.x;
  if (i >= ET) return;
  int src, dst;
  if (i < EE) { src = ei[i]; dst = ei[EE + i]; }
  else        { src = i - EE; dst = i - EE; }
  int pos = atomicAdd(&cur[dst], 1);
  csr[rs[dst] + pos] = src;
}

// ---------------- attention scalars layer 1 --------------------------------
__global__ __launch_bounds__(256) void k_att1(const float* __restrict__ h1,
                                              const float* __restrict__ as, const float* __restrict__ ad,
                                              float* __restrict__ a1s, float* __restrict__ a1d) {
  int lane = threadIdx.x & 63, wv = threadIdx.x >> 6;
  int n = blockIdx.x * 4 + wv;
  const float* hr = h1 + (long)n * 256;
  float4_ p;
  p.x = hr[lane] * as[lane] + hr[lane + 64] * as[lane + 64];
  p.y = hr[lane + 128] * as[lane + 128] + hr[lane + 192] * as[lane + 192];
  p.z = hr[lane] * ad[lane] + hr[lane + 64] * ad[lane + 64];
  p.w = hr[lane + 128] * ad[lane + 128] + hr[lane + 192] * ad[lane + 192];
  for (int off = 1; off < 64; off <<= 1) {
    p.x += __shfl_xor(p.x, off); p.y += __shfl_xor(p.y, off);
    p.z += __shfl_xor(p.z, off); p.w += __shfl_xor(p.w, off);
  }
  if (lane == 0) {
    a1s[n * 2] = p.x; a1s[n * 2 + 1] = p.y;
    a1d[n * 2] = p.z; a1d[n * 2 + 1] = p.w;
  }
}

// ---------------- GAT layer 1: softmax-aggregate + bias + elu --------------
__global__ __launch_bounds__(256) void k_gat1(const int* __restrict__ rs, const int* __restrict__ csr,
                                              const float* __restrict__ a1s, const float* __restrict__ a1d,
                                              const float* __restrict__ h1, const float* __restrict__ b1,
                                              float* __restrict__ x2) {
  int lane = threadIdx.x & 63, wv = threadIdx.x >> 6;
  int node = blockIdx.x * 4 + wv;
  int beg = rs[node], end = rs[node + 1];
  float ad0 = a1d[node * 2], ad1 = a1d[node * 2 + 1];
  float m0 = -1e30f, m1 = -1e30f;
  for (int i = beg + lane; i < end; i += 64) {
    int s = csr[i];
    float e0 = a1s[s * 2] + ad0;     e0 = (e0 > 0.f) ? e0 : 0.2f * e0;
    float e1 = a1s[s * 2 + 1] + ad1; e1 = (e1 > 0.f) ? e1 : 0.2f * e1;
    m0 = fmaxf(m0, e0); m1 = fmaxf(m1, e1);
  }
  for (int off = 1; off < 64; off <<= 1) {
    m0 = fmaxf(m0, __shfl_xor(m0, off));
    m1 = fmaxf(m1, __shfl_xor(m1, off));
  }
  int my4 = lane * 4;
  int myh = my4 >> 7;
  float mym = myh ? m1 : m0;
  float myad = myh ? ad1 : ad0;
  float4_ acc = {0.f, 0.f, 0.f, 0.f};
  float ps = 0.f;
  for (int i = beg; i < end; ++i) {
    int s = csr[i];
    float e = a1s[s * 2 + myh] + myad;
    e = (e > 0.f) ? e : 0.2f * e;
    float p = __expf(e - mym);
    ps += p;
    float4_ hv = *(const float4_*)(h1 + (long)s * 256 + my4);
    acc += p * hv;
  }
  for (int off = 1; off < 32; off <<= 1) ps += __shfl_xor(ps, off);
  float inv = 1.0f / (ps * 0.03125f + 1e-16f);
  float4_ o;
#pragma unroll
  for (int j = 0; j < 4; ++j) {
    float v = acc[j] * inv + b1[my4 + j];
    o[j] = (v > 0.f) ? v : expm1f(v);
  }
  *(float4_*)(x2 + (long)node * 256 + my4) = o;
}

// ---------------- h2 = x2 @ g2_W  + attention scalars layer 2 --------------
__global__ __launch_bounds__(256) void k_h2att2(const float* __restrict__ x2, const float* __restrict__ W2,
                                                const float* __restrict__ as2, const float* __restrict__ ad2,
                                                float* __restrict__ h2, float* __restrict__ a2s,
                                                float* __restrict__ a2d) {
  int lane = threadIdx.x & 63, wv = threadIdx.x >> 6;
  int n = blockIdx.x * 4 + wv;
  const float* xr = x2 + (long)n * 256;
  float4_ a = {0.f, 0.f, 0.f, 0.f};
  for (int k = lane; k < 256; k += 64) {
    float xv = xr[k];
    float4_ wr = *(const float4_*)(W2 + k * 4);
    a += xv * wr;
  }
  for (int off = 1; off < 64; off <<= 1) {
    a.x += __shfl_xor(a.x, off); a.y += __shfl_xor(a.y, off);
    a.z += __shfl_xor(a.z, off); a.w += __shfl_xor(a.w, off);
  }
  if (lane == 0) {
    *(float4_*)(h2 + n * 4) = a;
    a2s[n] = a.x * as2[0] + a.y * as2[1] + a.z * as2[2] + a.w * as2[3];
    a2d[n] = a.x * ad2[0] + a.y * ad2[1] + a.z * ad2[2] + a.w * ad2[3];
  }
}

// ---------------- GAT layer 2 -> final output ------------------------------
__global__ __launch_bounds__(256) void k_gat2(const int* __restrict__ rs, const int* __restrict__ csr,
                                              const float* __restrict__ a2s, const float* __restrict__ a2d,
                                              const float* __restrict__ h2, const float* __restrict__ b2,
                                              float* __restrict__ out) {
  int lane = threadIdx.x & 63, wv = threadIdx.x >> 6;
  int node = blockIdx.x * 4 + wv;
  int beg = rs[node], end = rs[node + 1];
  float adv = a2d[node];
  float m = -1e30f;
  for (int i = beg + lane; i < end; i += 64) {
    float e = a2s[csr[i]] + adv;
    e = (e > 0.f) ? e : 0.2f * e;
    m = fmaxf(m, e);
  }
  for (int off = 1; off < 64; off <<= 1) m = fmaxf(m, __shfl_xor(m, off));
  float4_ acc = {0.f, 0.f, 0.f, 0.f};
  float ps = 0.f;
  for (int i = beg + lane; i < end; i += 64) {
    int s = csr[i];
    float e = a2s[s] + adv;
    e = (e > 0.f) ? e : 0.2f * e;
    float p = __expf(e - m);
    ps += p;
    float4_ hv = *(const float4_*)(h2 + (long)s * 4);
    acc += p * hv;
  }
  for (int off = 1; off < 64; off <<= 1) {
    ps += __shfl_xor(ps, off);
    acc.x += __shfl_xor(acc.x, off); acc.y += __shfl_xor(acc.y, off);
    acc.z += __shfl_xor(acc.z, off); acc.w += __shfl_xor(acc.w, off);
  }
  if (lane == 0) {
    float inv = 1.0f / (ps + 1e-16f);
    out[node * 4 + 0] = acc.x * inv + b2[0];
    out[node * 4 + 1] = acc.y * inv + b2[1];
    out[node * 4 + 2] = acc.z * inv + b2[2];
    out[node * 4 + 3] = acc.w * inv + b2[3];
  }
}

extern "C" void kernel_launch(void* const* d_in, const int* in_sizes, int n_in,
                              void* d_out, int out_size, void* d_ws, size_t ws_size,
                              hipStream_t stream) {
  (void)in_sizes; (void)n_in; (void)out_size; (void)ws_size;
  const float* text = (const float*)d_in[0];
  const float* mel  = (const float*)d_in[1];
  const int*   ei   = (const int*)d_in[2];
  const float* melW = (const float*)d_in[3];
  const float* melb = (const float*)d_in[4];
  const float* catW = (const float*)d_in[5];
  const float* catb = (const float*)d_in[6];
  const float* g1W  = (const float*)d_in[7];
  const float* g1as = (const float*)d_in[8];
  const float* g1ad = (const float*)d_in[9];
  const float* g1b  = (const float*)d_in[10];
  const float* g2W  = (const float*)d_in[11];
  const float* g2as = (const float*)d_in[12];
  const float* g2ad = (const float*)d_in[13];
  const float* g2b  = (const float*)d_in[14];
  float* out = (float*)d_out;

  char* w = (char*)d_ws;
  size_t off = 0;
  auto alloc = [&](size_t bytes) -> char* {
    char* p = w + off;
    off += (bytes + 255) & ~(size_t)255;
    return p;
  };
  short* wmelH = (short*)alloc((size_t)MELK * 128 * 2);
  short* wmelL = (short*)alloc((size_t)MELK * 128 * 2);
  short* wcatH = (short*)alloc((size_t)896 * 128 * 2);
  short* wcatL = (short*)alloc((size_t)896 * 128 * 2);
  short* w1H   = (short*)alloc((size_t)128 * 256 * 2);
  short* w1L   = (short*)alloc((size_t)128 * 256 * 2);
  float* melfeat = (float*)alloc((size_t)NN * 128 * 4);
  float* x1      = (float*)alloc((size_t)NN * 128 * 4);
  float* h1      = (float*)alloc((size_t)NN * 256 * 4);
  float* x2      = (float*)alloc((size_t)NN * 256 * 4);
  float* h2      = (float*)alloc((size_t)NN * 4 * 4);
  float* a1s     = (float*)alloc((size_t)NN * 2 * 4);
  float* a1d     = (float*)alloc((size_t)NN * 2 * 4);
  float* a2s     = (float*)alloc((size_t)NN * 4);
  float* a2d     = (float*)alloc((size_t)NN * 4);
  int* counts    = (int*)alloc((size_t)NN * 4);
  int* rs        = (int*)alloc((size_t)(NN + 1) * 4);
  int* cursor    = (int*)alloc((size_t)NN * 4);
  int* csr       = (int*)alloc((size_t)ET * 4);

  hipMemsetAsync(counts, 0, (size_t)NN * 4, stream);
  hipMemsetAsync(cursor, 0, (size_t)NN * 4, stream);

  // weight prep
  k_prep_w<<<(MELK * 128 + 255) / 256, 256, 0, stream>>>(melW, MELK, 128, wmelH, wmelL);
  k_prep_w<<<(896 * 128 + 255) / 256, 256, 0, stream>>>(catW, 896, 128, wcatH, wcatL);
  k_prep_w<<<(128 * 256 + 255) / 256, 256, 0, stream>>>(g1W, 128, 256, w1H, w1L);

  // CSR build
  int egrid = (ET + 255) / 256;
  k_count<<<egrid, 256, 0, stream>>>(ei, counts);
  k_scan<<<1, 1024, 0, stream>>>(counts, rs, NN);
  k_fill<<<egrid, 256, 0, stream>>>(ei, rs, cursor, csr);

  // GEMMs
  dim3 g157(157, 1);
  k_gemm<<<g157, 256, 0, stream>>>(mel, MELK, nullptr, 0, wmelH, wmelL, MELK, melb, 1,
                                   melfeat, 128, NN);
  k_gemm<<<g157, 256, 0, stream>>>(text, TXTK, melfeat, 128, wcatH, wcatL, 896, catb, 2,
                                   x1, 128, NN);
  dim3 g157b(157, 2);
  k_gemm<<<g157b, 256, 0, stream>>>(x1, 128, nullptr, 0, w1H, w1L, 128, nullptr, 0,
                                    h1, 256, NN);

  // attention + aggregation
  k_att1<<<NN / 4, 256, 0, stream>>>(h1, g1as, g1ad, a1s, a1d);
  k_gat1<<<NN / 4, 256, 0, stream>>>(rs, csr, a1s, a1d, h1, g1b, x2);
  k_h2att2<<<NN / 4, 256, 0, stream>>>(x2, g2W, g2as, g2ad, h2, a2s, a2d);
  k_gat2<<<NN / 4, 256, 0, stream>>>(rs, csr, a2s, a2d, h2, g2b, out);
}

// Round 2
// 1117.431 us; speedup vs baseline: 1.1266x; 1.1266x over previous
//
#include <hip/hip_runtime.h>

#define NN   20000
#define EE   640000
#define ET   (EE + NN)
#define TXTK 768
#define MELK 6400
#define HIDC 128
#define LDSW 36   // LDS leading stride in shorts (72B = 18 banks -> 2-way on b128, free)

typedef float  float4_ __attribute__((ext_vector_type(4)));
typedef short  short4_ __attribute__((ext_vector_type(4)));
typedef short  short8_ __attribute__((ext_vector_type(8)));
typedef __bf16 bf16x8  __attribute__((ext_vector_type(8)));

__device__ __forceinline__ unsigned short bf_hi_trunc(float f) {
  return (unsigned short)(__float_as_uint(f) >> 16);
}
__device__ __forceinline__ float bf_to_f(unsigned short s) {
  return __uint_as_float(((unsigned)s) << 16);
}
__device__ __forceinline__ unsigned short bf_rne(float f) {
  unsigned u = __float_as_uint(f);
  u += 0x7FFFu + ((u >> 16) & 1u);
  return (unsigned short)(u >> 16);
}

// ---------------- weight prep: fp32 [K,N] -> bf16 hi/lo transposed [N,K] ----
__global__ __launch_bounds__(256) void k_prep_w(const float* __restrict__ W, int K, int N,
                                                short* __restrict__ hi, short* __restrict__ lo) {
  int t = blockIdx.x * 256 + threadIdx.x;
  if (t >= K * N) return;
  int k = t / N, n = t - k * N;
  float f = W[t];
  unsigned short h = bf_hi_trunc(f);
  unsigned short l = bf_rne(f - bf_to_f(h));
  hi[(long)n * K + k] = (short)h;
  lo[(long)n * K + k] = (short)l;
}

// ---------------- split-bf16 MFMA GEMM with split-K + reg prefetch ----------
// A row = [A1 row (K1) | A2 row (K2)], fp32, converted to hi/lo on the fly.
// Bhi/Blo are [Ntot, Ktot] (pre-transposed). Tile 128x128, K-step 32.
// blockIdx.z = K-chunk; nchunks>1 -> raw partial store to C + part*M*ldC.
__global__ __launch_bounds__(256) void k_gemm(
    const float* __restrict__ A1, int K1, const float* __restrict__ A2, int K2,
    const short* __restrict__ Bhi, const short* __restrict__ Blo, int Ktot,
    int chunkK, const float* __restrict__ bias, int act,
    float* __restrict__ C, int ldC, int M, int nchunks) {
  __shared__ short lAhi[128 * LDSW], lAlo[128 * LDSW], lBhi[128 * LDSW], lBlo[128 * LDSW];
  int t = threadIdx.x;
  int lane = t & 63, wv = t >> 6;
  int m16 = lane & 15, q = lane >> 4;
  int bm = blockIdx.x;
  int col0 = blockIdx.y * 128;
  int part = blockIdx.z;
  int ks0 = part * chunkK;
  int kend = ks0 + chunkK;
  if (nchunks > 1) C += (size_t)part * M * ldC;

  float4_ acc[8][2];
#pragma unroll
  for (int rt = 0; rt < 8; ++rt)
#pragma unroll
    for (int ct = 0; ct < 2; ++ct) acc[rt][ct] = (float4_){0.f, 0.f, 0.f, 0.f};

  // A-load row indices (clamped)
  long rg[4];
#pragma unroll
  for (int j = 0; j < 4; ++j) {
    long r = (long)bm * 128 + (t >> 3) + j * 32;
    rg[j] = (r >= M) ? (M - 1) : r;
  }

  float4_ pa[4];
  short8_ pbh[2], pbl[2];

  auto loadA = [&](int ks) {
    int col = ks + (t & 7) * 4;
#pragma unroll
    for (int j = 0; j < 4; ++j) {
      const float* sp = (col < K1) ? (A1 + rg[j] * K1 + col) : (A2 + rg[j] * K2 + (col - K1));
      pa[j] = *(const float4_*)sp;
    }
  };
  auto loadB = [&](int ks) {
#pragma unroll
    for (int j = 0; j < 2; ++j) {
      int f = t + j * 256;
      int colb = f >> 2, k8 = f & 3;
      long go = (long)(col0 + colb) * Ktot + ks + k8 * 8;
      pbh[j] = *(const short8_*)(Bhi + go);
      pbl[j] = *(const short8_*)(Blo + go);
    }
  };

  loadA(ks0);
  loadB(ks0);

  for (int ks = ks0; ks < kend; ks += 32) {
    __syncthreads();
    // commit prefetched regs into LDS (fp32 -> hi/lo bf16 for A)
#pragma unroll
    for (int j = 0; j < 4; ++j) {
      int row = (t >> 3) + j * 32, c4 = t & 7;
      short4_ h, l;
#pragma unroll
      for (int c = 0; c < 4; ++c) {
        unsigned short hh = bf_hi_trunc(pa[j][c]);
        h[c] = (short)hh;
        l[c] = (short)bf_rne(pa[j][c] - bf_to_f(hh));
      }
      *(short4_*)&lAhi[row * LDSW + c4 * 4] = h;
      *(short4_*)&lAlo[row * LDSW + c4 * 4] = l;
    }
#pragma unroll
    for (int j = 0; j < 2; ++j) {
      int f = t + j * 256;
      int colb = f >> 2, k8 = f & 3;
      *(short8_*)&lBhi[colb * LDSW + k8 * 8] = pbh[j];
      *(short8_*)&lBlo[colb * LDSW + k8 * 8] = pbl[j];
    }
    __syncthreads();

    // issue next tile's global loads; latency hides behind the MFMA block
    int kn = (ks + 32 < kend) ? (ks + 32) : ks;
    loadA(kn);
    loadB(kn);

    bf16x8 bh[2], bl[2];
#pragma unroll
    for (int ct = 0; ct < 2; ++ct) {
      int cb = (wv * 32 + ct * 16 + m16) * LDSW + q * 8;
      bh[ct] = *(const bf16x8*)&lBhi[cb];
      bl[ct] = *(const bf16x8*)&lBlo[cb];
    }
#pragma unroll
    for (int rt = 0; rt < 8; ++rt) {
      int ab = (rt * 16 + m16) * LDSW + q * 8;
      bf16x8 ah = *(const bf16x8*)&lAhi[ab];
      bf16x8 al = *(const bf16x8*)&lAlo[ab];
#pragma unroll
      for (int ct = 0; ct < 2; ++ct) {
        acc[rt][ct] = __builtin_amdgcn_mfma_f32_16x16x32_bf16(ah, bh[ct], acc[rt][ct], 0, 0, 0);
        acc[rt][ct] = __builtin_amdgcn_mfma_f32_16x16x32_bf16(ah, bl[ct], acc[rt][ct], 0, 0, 0);
        acc[rt][ct] = __builtin_amdgcn_mfma_f32_16x16x32_bf16(al, bh[ct], acc[rt][ct], 0, 0, 0);
      }
    }
  }

  // epilogue: C layout col=lane&15, row=q*4+reg
#pragma unroll
  for (int rt = 0; rt < 8; ++rt) {
#pragma unroll
    for (int ct = 0; ct < 2; ++ct) {
      int colg = col0 + wv * 32 + ct * 16 + m16;
      float b = (nchunks == 1 && bias) ? bias[colg] : 0.0f;
#pragma unroll
      for (int r = 0; r < 4; ++r) {
        int rowg = bm * 128 + rt * 16 + q * 4 + r;
        if (rowg < M) {
          float v = acc[rt][ct][r] + b;
          if (nchunks == 1) {
            if (act == 1) v = fmaxf(v, 0.0f);
            else if (act == 2) v = (v > 0.0f) ? v : expm1f(v);
          }
          C[(long)rowg * ldC + colg] = v;
        }
      }
    }
  }
}

// ---------------- split-K epilogue: sum parts + bias + act ------------------
__global__ __launch_bounds__(256) void k_epi(const float* __restrict__ P, long pstride, int nparts,
                                             const float* __restrict__ bias, int act,
                                             float* __restrict__ C, int Ncols, long total) {
  long idx4 = ((long)blockIdx.x * 256 + threadIdx.x) * 4;
  if (idx4 >= total) return;
  float4_ s = *(const float4_*)(P + idx4);
#pragma unroll 3
  for (int p = 1; p < nparts; ++p) s += *(const float4_*)(P + (long)p * pstride + idx4);
  int col = (int)(idx4 & (Ncols - 1));
  float4_ b = *(const float4_*)(bias + col);
  s += b;
#pragma unroll
  for (int c = 0; c < 4; ++c) {
    if (act == 1) s[c] = fmaxf(s[c], 0.0f);
    else if (act == 2) s[c] = (s[c] > 0.0f) ? s[c] : expm1f(s[c]);
  }
  *(float4_*)(C + idx4) = s;
}

// ---------------- CSR build ------------------------------------------------
__global__ __launch_bounds__(256) void k_count(const int* __restrict__ ei, int* __restrict__ cnt) {
  int i = blockIdx.x * 256 + threadIdx.x;
  if (i >= ET) return;
  int dst = (i < EE) ? ei[EE + i] : (i - EE);
  atomicAdd(&cnt[dst], 1);
}

__global__ __launch_bounds__(1024) void k_scan(const int* __restrict__ cnt, int* __restrict__ rs, int n) {
  __shared__ int wsum[16];
  __shared__ int carry;
  int tid = threadIdx.x, lane = tid & 63, w = tid >> 6;
  if (tid == 0) { carry = 0; rs[0] = 0; }
  __syncthreads();
  int nch = (n + 1023) >> 10;
  for (int c = 0; c < nch; ++c) {
    int i = (c << 10) + tid;
    int v = (i < n) ? cnt[i] : 0;
    int sv = v;
#pragma unroll
    for (int off = 1; off < 64; off <<= 1) { int t2 = __shfl_up(sv, off); if (lane >= off) sv += t2; }
    if (lane == 63) wsum[w] = sv;
    __syncthreads();
    if (w == 0) {
      int s = (lane < 16) ? wsum[lane] : 0;
#pragma unroll
      for (int off = 1; off < 16; off <<= 1) { int t2 = __shfl_up(s, off); if (lane >= off) s += t2; }
      if (lane < 16) wsum[lane] = s;
    }
    __syncthreads();
    int base = carry + ((w > 0) ? wsum[w - 1] : 0);
    int total = wsum[15];
    if (i < n) rs[i + 1] = base + sv;
    __syncthreads();
    if (tid == 0) carry += total;
    __syncthreads();
  }
}

__global__ __launch_bounds__(256) void k_fill(const int* __restrict__ ei, const int* __restrict__ rs,
                                              int* __restrict__ cur, int* __restrict__ csr) {
  int i = blockIdx.x * 256 + threadIdx.x;
  if (i >= ET) return;
  int src, dst;
  if (i < EE) { src = ei[i]; dst = ei[EE + i]; }
  else        { src = i - EE; dst = i - EE; }
  int pos = atomicAdd(&cur[dst], 1);
  csr[rs[dst] + pos] = src;
}

// ---------------- attention scalars layer 1 --------------------------------
__global__ __launch_bounds__(256) void k_att1(const float* __restrict__ h1,
                                              const float* __restrict__ as, const float* __restrict__ ad,
                                              float* __restrict__ a1s, float* __restrict__ a1d) {
  int lane = threadIdx.x & 63, wv = threadIdx.x >> 6;
  int n = blockIdx.x * 4 + wv;
  const float* hr = h1 + (long)n * 256;
  float4_ p;
  p.x = hr[lane] * as[lane] + hr[lane + 64] * as[lane + 64];
  p.y = hr[lane + 128] * as[lane + 128] + hr[lane + 192] * as[lane + 192];
  p.z = hr[lane] * ad[lane] + hr[lane + 64] * ad[lane + 64];
  p.w = hr[lane + 128] * ad[lane + 128] + hr[lane + 192] * ad[lane + 192];
  for (int off = 1; off < 64; off <<= 1) {
    p.x += __shfl_xor(p.x, off); p.y += __shfl_xor(p.y, off);
    p.z += __shfl_xor(p.z, off); p.w += __shfl_xor(p.w, off);
  }
  if (lane == 0) {
    a1s[n * 2] = p.x; a1s[n * 2 + 1] = p.y;
    a1d[n * 2] = p.z; a1d[n * 2 + 1] = p.w;
  }
}

// ---------------- GAT layer 1: softmax-aggregate + bias + elu --------------
__global__ __launch_bounds__(256) void k_gat1(const int* __restrict__ rs, const int* __restrict__ csr,
                                              const float* __restrict__ a1s, const float* __restrict__ a1d,
                                              const float* __restrict__ h1, const float* __restrict__ b1,
                                              float* __restrict__ x2) {
  int lane = threadIdx.x & 63, wv = threadIdx.x >> 6;
  int node = blockIdx.x * 4 + wv;
  int beg = rs[node], end = rs[node + 1];
  float ad0 = a1d[node * 2], ad1 = a1d[node * 2 + 1];
  float m0 = -1e30f, m1 = -1e30f;
  for (int i = beg + lane; i < end; i += 64) {
    int s = csr[i];
    float e0 = a1s[s * 2] + ad0;     e0 = (e0 > 0.f) ? e0 : 0.2f * e0;
    float e1 = a1s[s * 2 + 1] + ad1; e1 = (e1 > 0.f) ? e1 : 0.2f * e1;
    m0 = fmaxf(m0, e0); m1 = fmaxf(m1, e1);
  }
  for (int off = 1; off < 64; off <<= 1) {
    m0 = fmaxf(m0, __shfl_xor(m0, off));
    m1 = fmaxf(m1, __shfl_xor(m1, off));
  }
  int my4 = lane * 4;
  int myh = my4 >> 7;
  float mym = myh ? m1 : m0;
  float myad = myh ? ad1 : ad0;
  float4_ acc = {0.f, 0.f, 0.f, 0.f};
  float ps = 0.f;
  for (int i = beg; i < end; ++i) {
    int s = csr[i];
    float e = a1s[s * 2 + myh] + myad;
    e = (e > 0.f) ? e : 0.2f * e;
    float p = __expf(e - mym);
    ps += p;
    float4_ hv = *(const float4_*)(h1 + (long)s * 256 + my4);
    acc += p * hv;
  }
  for (int off = 1; off < 32; off <<= 1) ps += __shfl_xor(ps, off);
  float inv = 1.0f / (ps * 0.03125f + 1e-16f);
  float4_ o;
#pragma unroll
  for (int j = 0; j < 4; ++j) {
    float v = acc[j] * inv + b1[my4 + j];
    o[j] = (v > 0.f) ? v : expm1f(v);
  }
  *(float4_*)(x2 + (long)node * 256 + my4) = o;
}

// ---------------- h2 = x2 @ g2_W  + attention scalars layer 2 --------------
__global__ __launch_bounds__(256) void k_h2att2(const float* __restrict__ x2, const float* __restrict__ W2,
                                                const float* __restrict__ as2, const float* __restrict__ ad2,
                                                float* __restrict__ h2, float* __restrict__ a2s,
                                                float* __restrict__ a2d) {
  int lane = threadIdx.x & 63, wv = threadIdx.x >> 6;
  int n = blockIdx.x * 4 + wv;
  const float* xr = x2 + (long)n * 256;
  float4_ a = {0.f, 0.f, 0.f, 0.f};
  for (int k = lane; k < 256; k += 64) {
    float xv = xr[k];
    float4_ wr = *(const float4_*)(W2 + k * 4);
    a += xv * wr;
  }
  for (int off = 1; off < 64; off <<= 1) {
    a.x += __shfl_xor(a.x, off); a.y += __shfl_xor(a.y, off);
    a.z += __shfl_xor(a.z, off); a.w += __shfl_xor(a.w, off);
  }
  if (lane == 0) {
    *(float4_*)(h2 + n * 4) = a;
    a2s[n] = a.x * as2[0] + a.y * as2[1] + a.z * as2[2] + a.w * as2[3];
    a2d[n] = a.x * ad2[0] + a.y * ad2[1] + a.z * ad2[2] + a.w * ad2[3];
  }
}

// ---------------- GAT layer 2 -> final output ------------------------------
__global__ __launch_bounds__(256) void k_gat2(const int* __restrict__ rs, const int* __restrict__ csr,
                                              const float* __restrict__ a2s, const float* __restrict__ a2d,
                                              const float* __restrict__ h2, const float* __restrict__ b2,
                                              float* __restrict__ out) {
  int lane = threadIdx.x & 63, wv = threadIdx.x >> 6;
  int node = blockIdx.x * 4 + wv;
  int beg = rs[node], end = rs[node + 1];
  float adv = a2d[node];
  float m = -1e30f;
  for (int i = beg + lane; i < end; i += 64) {
    float e = a2s[csr[i]] + adv;
    e = (e > 0.f) ? e : 0.2f * e;
    m = fmaxf(m, e);
  }
  for (int off = 1; off < 64; off <<= 1) m = fmaxf(m, __shfl_xor(m, off));
  float4_ acc = {0.f, 0.f, 0.f, 0.f};
  float ps = 0.f;
  for (int i = beg + lane; i < end; i += 64) {
    int s = csr[i];
    float e = a2s[s] + adv;
    e = (e > 0.f) ? e : 0.2f * e;
    float p = __expf(e - m);
    ps += p;
    float4_ hv = *(const float4_*)(h2 + (long)s * 4);
    acc += p * hv;
  }
  for (int off = 1; off < 64; off <<= 1) {
    ps += __shfl_xor(ps, off);
    acc.x += __shfl_xor(acc.x, off); acc.y += __shfl_xor(acc.y, off);
    acc.z += __shfl_xor(acc.z, off); acc.w += __shfl_xor(acc.w, off);
  }
  if (lane == 0) {
    float inv = 1.0f / (ps + 1e-16f);
    out[node * 4 + 0] = acc.x * inv + b2[0];
    out[node * 4 + 1] = acc.y * inv + b2[1];
    out[node * 4 + 2] = acc.z * inv + b2[2];
    out[node * 4 + 3] = acc.w * inv + b2[3];
  }
}

extern "C" void kernel_launch(void* const* d_in, const int* in_sizes, int n_in,
                              void* d_out, int out_size, void* d_ws, size_t ws_size,
                              hipStream_t stream) {
  (void)in_sizes; (void)n_in; (void)out_size; (void)ws_size;
  const float* text = (const float*)d_in[0];
  const float* mel  = (const float*)d_in[1];
  const int*   ei   = (const int*)d_in[2];
  const float* melW = (const float*)d_in[3];
  const float* melb = (const float*)d_in[4];
  const float* catW = (const float*)d_in[5];
  const float* catb = (const float*)d_in[6];
  const float* g1W  = (const float*)d_in[7];
  const float* g1as = (const float*)d_in[8];
  const float* g1ad = (const float*)d_in[9];
  const float* g1b  = (const float*)d_in[10];
  const float* g2W  = (const float*)d_in[11];
  const float* g2as = (const float*)d_in[12];
  const float* g2ad = (const float*)d_in[13];
  const float* g2b  = (const float*)d_in[14];
  float* out = (float*)d_out;

  char* w = (char*)d_ws;
  size_t off = 0;
  auto alloc = [&](size_t bytes) -> char* {
    char* p = w + off;
    off += (bytes + 255) & ~(size_t)255;
    return p;
  };
  short* wmelH = (short*)alloc((size_t)MELK * 128 * 2);
  short* wmelL = (short*)alloc((size_t)MELK * 128 * 2);
  short* wcatH = (short*)alloc((size_t)896 * 128 * 2);
  short* wcatL = (short*)alloc((size_t)896 * 128 * 2);
  short* w1H   = (short*)alloc((size_t)128 * 256 * 2);
  short* w1L   = (short*)alloc((size_t)128 * 256 * 2);
  float* gtmp    = (float*)alloc((size_t)4 * NN * 128 * 4);  // split-K partials (shared)
  float* melfeat = (float*)alloc((size_t)NN * 128 * 4);
  float* x1      = (float*)alloc((size_t)NN * 128 * 4);
  float* h1      = (float*)alloc((size_t)NN * 256 * 4);
  float* x2      = (float*)alloc((size_t)NN * 256 * 4);
  float* h2      = (float*)alloc((size_t)NN * 4 * 4);
  float* a1s     = (float*)alloc((size_t)NN * 2 * 4);
  float* a1d     = (float*)alloc((size_t)NN * 2 * 4);
  float* a2s     = (float*)alloc((size_t)NN * 4);
  float* a2d     = (float*)alloc((size_t)NN * 4);
  int* counts    = (int*)alloc((size_t)NN * 4);
  int* rs        = (int*)alloc((size_t)(NN + 1) * 4);
  int* cursor    = (int*)alloc((size_t)NN * 4);
  int* csr       = (int*)alloc((size_t)ET * 4);

  hipMemsetAsync(counts, 0, (size_t)NN * 4, stream);
  hipMemsetAsync(cursor, 0, (size_t)NN * 4, stream);

  // weight prep
  k_prep_w<<<(MELK * 128 + 255) / 256, 256, 0, stream>>>(melW, MELK, 128, wmelH, wmelL);
  k_prep_w<<<(896 * 128 + 255) / 256, 256, 0, stream>>>(catW, 896, 128, wcatH, wcatL);
  k_prep_w<<<(128 * 256 + 255) / 256, 256, 0, stream>>>(g1W, 128, 256, w1H, w1L);

  // CSR build
  int egrid = (ET + 255) / 256;
  k_count<<<egrid, 256, 0, stream>>>(ei, counts);
  k_scan<<<1, 1024, 0, stream>>>(counts, rs, NN);
  k_fill<<<egrid, 256, 0, stream>>>(ei, rs, cursor, csr);

  long tot128 = (long)NN * 128;
  int epigrid = (int)((tot128 / 4 + 255) / 256);

  // mel GEMM: K=6400, split-K x4 (chunks of 1600)
  k_gemm<<<dim3(157, 1, 4), 256, 0, stream>>>(mel, MELK, nullptr, 0, wmelH, wmelL, MELK,
                                              1600, nullptr, 0, gtmp, 128, NN, 4);
  k_epi<<<epigrid, 256, 0, stream>>>(gtmp, tot128, 4, melb, 1, melfeat, 128, tot128);

  // concat GEMM: K=896, split-K x2 (chunks of 448)
  k_gemm<<<dim3(157, 1, 2), 256, 0, stream>>>(text, TXTK, melfeat, 128, wcatH, wcatL, 896,
                                              448, nullptr, 0, gtmp, 128, NN, 2);
  k_epi<<<epigrid, 256, 0, stream>>>(gtmp, tot128, 2, catb, 2, x1, 128, tot128);

  // g1 GEMM: K=128, 2 col-blocks, single chunk, no act
  k_gemm<<<dim3(157, 2, 1), 256, 0, stream>>>(x1, 128, nullptr, 0, w1H, w1L, 128,
                                              128, nullptr, 0, h1, 256, NN, 1);

  // attention + aggregation
  k_att1<<<NN / 4, 256, 0, stream>>>(h1, g1as, g1ad, a1s, a1d);
  k_gat1<<<NN / 4, 256, 0, stream>>>(rs, csr, a1s, a1d, h1, g1b, x2);
  k_h2att2<<<NN / 4, 256, 0, stream>>>(x2, g2W, g2as, g2ad, h2, a2s, a2d);
  k_gat2<<<NN / 4, 256, 0, stream>>>(rs, csr, a2s, a2d, h2, g2b, out);
}

// Round 3
// 1020.897 us; speedup vs baseline: 1.2331x; 1.0946x over previous
//
#include <hip/hip_runtime.h>

#define NN   20000
#define EE   640000
#define ET   (EE + NN)
#define TXTK 768
#define MELK 6400
#define LDSW 36   // LDS leading stride in halves (72B = 18 banks -> 2-way on b128, free)

typedef float    float4_ __attribute__((ext_vector_type(4)));
typedef short    short4_ __attribute__((ext_vector_type(4)));
typedef short    short8_ __attribute__((ext_vector_type(8)));
typedef _Float16 half4_  __attribute__((ext_vector_type(4)));
typedef _Float16 half8_  __attribute__((ext_vector_type(8)));

// ---------------- weight prep: fp32 [K,N] -> f16 transposed [N,K] ----------
__global__ __launch_bounds__(256) void k_prep_w(const float* __restrict__ W, int K, int N,
                                                _Float16* __restrict__ o) {
  int t = blockIdx.x * 256 + threadIdx.x;
  if (t >= K * N) return;
  int k = t / N, n = t - k * N;
  o[(long)n * K + k] = (_Float16)W[t];
}

// ---------------- f16 MFMA GEMM with split-K + register prefetch ------------
// A row = [A1 row (K1) | A2 row (K2)], fp32 -> f16 on the fly.
// Bf is [Ntot, Ktot] f16 (pre-transposed). Tile 128x128, K-step 32.
// blockIdx.z = K-chunk; nchunks>1 -> fp32 partial store to C + part*M*ldC.
// outHalf: write C as f16 (only valid with nchunks==1).
__global__ __launch_bounds__(256) void k_gemm(
    const float* __restrict__ A1, int K1, const float* __restrict__ A2, int K2,
    const _Float16* __restrict__ Bf, int Ktot,
    int chunkK, const float* __restrict__ bias, int act,
    void* __restrict__ Cv, int ldC, int M, int nchunks, int outHalf) {
  __shared__ _Float16 lA[128 * LDSW], lB[128 * LDSW];
  int t = threadIdx.x;
  int lane = t & 63, wv = t >> 6;
  int m16 = lane & 15, q = lane >> 4;
  int bm = blockIdx.x;
  int col0 = blockIdx.y * 128;
  int part = blockIdx.z;
  int ks0 = part * chunkK;
  int kend = ks0 + chunkK;

  float4_ acc[8][2];
#pragma unroll
  for (int rt = 0; rt < 8; ++rt)
#pragma unroll
    for (int ct = 0; ct < 2; ++ct) acc[rt][ct] = (float4_){0.f, 0.f, 0.f, 0.f};

  long rg[4];
#pragma unroll
  for (int j = 0; j < 4; ++j) {
    long r = (long)bm * 128 + (t >> 3) + j * 32;
    rg[j] = (r >= M) ? (M - 1) : r;
  }

  float4_ pa[4];
  short8_ pb[2];

  auto loadA = [&](int ks) {
    int col = ks + (t & 7) * 4;
#pragma unroll
    for (int j = 0; j < 4; ++j) {
      const float* sp = (col < K1) ? (A1 + rg[j] * K1 + col) : (A2 + rg[j] * K2 + (col - K1));
      pa[j] = *(const float4_*)sp;
    }
  };
  auto loadB = [&](int ks) {
#pragma unroll
    for (int j = 0; j < 2; ++j) {
      int f = t + j * 256;
      int colb = f >> 2, k8 = f & 3;
      long go = (long)(col0 + colb) * Ktot + ks + k8 * 8;
      pb[j] = *(const short8_*)(Bf + go);
    }
  };

  loadA(ks0);
  loadB(ks0);

  for (int ks = ks0; ks < kend; ks += 32) {
    __syncthreads();
#pragma unroll
    for (int j = 0; j < 4; ++j) {
      int row = (t >> 3) + j * 32, c4 = t & 7;
      half4_ h;
#pragma unroll
      for (int c = 0; c < 4; ++c) h[c] = (_Float16)pa[j][c];
      *(half4_*)&lA[row * LDSW + c4 * 4] = h;
    }
#pragma unroll
    for (int j = 0; j < 2; ++j) {
      int f = t + j * 256;
      int colb = f >> 2, k8 = f & 3;
      *(short8_*)&lB[colb * LDSW + k8 * 8] = pb[j];
    }
    __syncthreads();

    // prefetch next tile during MFMA block
    int kn = (ks + 32 < kend) ? (ks + 32) : ks;
    loadA(kn);
    loadB(kn);

    half8_ bfr[2];
#pragma unroll
    for (int ct = 0; ct < 2; ++ct)
      bfr[ct] = *(const half8_*)&lB[(wv * 32 + ct * 16 + m16) * LDSW + q * 8];
#pragma unroll
    for (int rt = 0; rt < 8; ++rt) {
      half8_ ah = *(const half8_*)&lA[(rt * 16 + m16) * LDSW + q * 8];
#pragma unroll
      for (int ct = 0; ct < 2; ++ct)
        acc[rt][ct] = __builtin_amdgcn_mfma_f32_16x16x32_f16(ah, bfr[ct], acc[rt][ct], 0, 0, 0);
    }
  }

  // epilogue: C layout col=lane&15, row=q*4+reg
#pragma unroll
  for (int rt = 0; rt < 8; ++rt) {
#pragma unroll
    for (int ct = 0; ct < 2; ++ct) {
      int colg = col0 + wv * 32 + ct * 16 + m16;
      float b = (nchunks == 1 && bias) ? bias[colg] : 0.0f;
#pragma unroll
      for (int r = 0; r < 4; ++r) {
        int rowg = bm * 128 + rt * 16 + q * 4 + r;
        if (rowg < M) {
          float v = acc[rt][ct][r] + b;
          if (nchunks == 1) {
            if (act == 1) v = fmaxf(v, 0.0f);
            else if (act == 2) v = (v > 0.0f) ? v : expm1f(v);
          }
          long idx = (long)rowg * ldC + colg;
          if (outHalf) ((_Float16*)Cv)[idx] = (_Float16)v;
          else ((float*)Cv)[(size_t)(nchunks > 1 ? part : 0) * M * ldC + idx] = v;
        }
      }
    }
  }
}

// ---------------- split-K epilogue: sum parts + bias + act ------------------
__global__ __launch_bounds__(256) void k_epi(const float* __restrict__ P, long pstride, int nparts,
                                             const float* __restrict__ bias, int act,
                                             float* __restrict__ C, int Ncols, long total) {
  long idx4 = ((long)blockIdx.x * 256 + threadIdx.x) * 4;
  if (idx4 >= total) return;
  float4_ s = *(const float4_*)(P + idx4);
#pragma unroll 3
  for (int p = 1; p < nparts; ++p) s += *(const float4_*)(P + (long)p * pstride + idx4);
  int col = (int)(idx4 & (Ncols - 1));
  float4_ b = *(const float4_*)(bias + col);
  s += b;
#pragma unroll
  for (int c = 0; c < 4; ++c) {
    if (act == 1) s[c] = fmaxf(s[c], 0.0f);
    else if (act == 2) s[c] = (s[c] > 0.0f) ? s[c] : expm1f(s[c]);
  }
  *(float4_*)(C + idx4) = s;
}

// ---------------- CSR build ------------------------------------------------
__global__ __launch_bounds__(256) void k_count(const int* __restrict__ ei, int* __restrict__ cnt) {
  int i = blockIdx.x * 256 + threadIdx.x;
  if (i >= ET) return;
  int dst = (i < EE) ? ei[EE + i] : (i - EE);
  atomicAdd(&cnt[dst], 1);
}

__global__ __launch_bounds__(1024) void k_scan(const int* __restrict__ cnt, int* __restrict__ rs, int n) {
  __shared__ int wsum[16];
  __shared__ int carry;
  int tid = threadIdx.x, lane = tid & 63, w = tid >> 6;
  if (tid == 0) { carry = 0; rs[0] = 0; }
  __syncthreads();
  int nch = (n + 1023) >> 10;
  for (int c = 0; c < nch; ++c) {
    int i = (c << 10) + tid;
    int v = (i < n) ? cnt[i] : 0;
    int sv = v;
#pragma unroll
    for (int off = 1; off < 64; off <<= 1) { int t2 = __shfl_up(sv, off); if (lane >= off) sv += t2; }
    if (lane == 63) wsum[w] = sv;
    __syncthreads();
    if (w == 0) {
      int s = (lane < 16) ? wsum[lane] : 0;
#pragma unroll
      for (int off = 1; off < 16; off <<= 1) { int t2 = __shfl_up(s, off); if (lane >= off) s += t2; }
      if (lane < 16) wsum[lane] = s;
    }
    __syncthreads();
    int base = carry + ((w > 0) ? wsum[w - 1] : 0);
    int total = wsum[15];
    if (i < n) rs[i + 1] = base + sv;
    __syncthreads();
    if (tid == 0) carry += total;
    __syncthreads();
  }
}

__global__ __launch_bounds__(256) void k_fill(const int* __restrict__ ei, const int* __restrict__ rs,
                                              int* __restrict__ cur, int* __restrict__ csr) {
  int i = blockIdx.x * 256 + threadIdx.x;
  if (i >= ET) return;
  int src, dst;
  if (i < EE) { src = ei[i]; dst = ei[EE + i]; }
  else        { src = i - EE; dst = i - EE; }
  int pos = atomicAdd(&cur[dst], 1);
  csr[rs[dst] + pos] = src;
}

// ---------------- attention scalars layer 1 (h1 is f16) --------------------
__global__ __launch_bounds__(256) void k_att1(const _Float16* __restrict__ h1,
                                              const float* __restrict__ as, const float* __restrict__ ad,
                                              float* __restrict__ a1s, float* __restrict__ a1d) {
  int lane = threadIdx.x & 63, wv = threadIdx.x >> 6;
  int n = blockIdx.x * 4 + wv;
  const _Float16* hr = h1 + (long)n * 256;
  float h0 = (float)hr[lane],       h1v = (float)hr[lane + 64];
  float h2 = (float)hr[lane + 128], h3 = (float)hr[lane + 192];
  float4_ p;
  p.x = h0 * as[lane] + h1v * as[lane + 64];
  p.y = h2 * as[lane + 128] + h3 * as[lane + 192];
  p.z = h0 * ad[lane] + h1v * ad[lane + 64];
  p.w = h2 * ad[lane + 128] + h3 * ad[lane + 192];
  for (int off = 1; off < 64; off <<= 1) {
    p.x += __shfl_xor(p.x, off); p.y += __shfl_xor(p.y, off);
    p.z += __shfl_xor(p.z, off); p.w += __shfl_xor(p.w, off);
  }
  if (lane == 0) {
    a1s[n * 2] = p.x; a1s[n * 2 + 1] = p.y;
    a1d[n * 2] = p.z; a1d[n * 2 + 1] = p.w;
  }
}

// ---------------- GAT layer 1: softmax-aggregate + bias + elu --------------
__global__ __launch_bounds__(256) void k_gat1(const int* __restrict__ rs, const int* __restrict__ csr,
                                              const float* __restrict__ a1s, const float* __restrict__ a1d,
                                              const _Float16* __restrict__ h1, const float* __restrict__ b1,
                                              float* __restrict__ x2) {
  int lane = threadIdx.x & 63, wv = threadIdx.x >> 6;
  int node = blockIdx.x * 4 + wv;
  int beg = rs[node], end = rs[node + 1];
  float ad0 = a1d[node * 2], ad1 = a1d[node * 2 + 1];
  float m0 = -1e30f, m1 = -1e30f;
  for (int i = beg + lane; i < end; i += 64) {
    int s = csr[i];
    float e0 = a1s[s * 2] + ad0;     e0 = (e0 > 0.f) ? e0 : 0.2f * e0;
    float e1 = a1s[s * 2 + 1] + ad1; e1 = (e1 > 0.f) ? e1 : 0.2f * e1;
    m0 = fmaxf(m0, e0); m1 = fmaxf(m1, e1);
  }
  for (int off = 1; off < 64; off <<= 1) {
    m0 = fmaxf(m0, __shfl_xor(m0, off));
    m1 = fmaxf(m1, __shfl_xor(m1, off));
  }
  int my4 = lane * 4;
  int myh = my4 >> 7;
  float mym = myh ? m1 : m0;
  float myad = myh ? ad1 : ad0;
  float4_ acc = {0.f, 0.f, 0.f, 0.f};
  float ps = 0.f;
  for (int i = beg; i < end; ++i) {
    int s = csr[i];
    float e = a1s[s * 2 + myh] + myad;
    e = (e > 0.f) ? e : 0.2f * e;
    float p = __expf(e - mym);
    ps += p;
    half4_ hv = *(const half4_*)(h1 + (long)s * 256 + my4);
#pragma unroll
    for (int j = 0; j < 4; ++j) acc[j] += p * (float)hv[j];
  }
  for (int off = 1; off < 32; off <<= 1) ps += __shfl_xor(ps, off);
  float inv = 1.0f / (ps * 0.03125f + 1e-16f);
  float4_ o;
#pragma unroll
  for (int j = 0; j < 4; ++j) {
    float v = acc[j] * inv + b1[my4 + j];
    o[j] = (v > 0.f) ? v : expm1f(v);
  }
  *(float4_*)(x2 + (long)node * 256 + my4) = o;
}

// ---------------- h2 = x2 @ g2_W  + attention scalars layer 2 --------------
__global__ __launch_bounds__(256) void k_h2att2(const float* __restrict__ x2, const float* __restrict__ W2,
                                                const float* __restrict__ as2, const float* __restrict__ ad2,
                                                float* __restrict__ h2, float* __restrict__ a2s,
                                                float* __restrict__ a2d) {
  int lane = threadIdx.x & 63, wv = threadIdx.x >> 6;
  int n = blockIdx.x * 4 + wv;
  const float* xr = x2 + (long)n * 256;
  float4_ a = {0.f, 0.f, 0.f, 0.f};
  for (int k = lane; k < 256; k += 64) {
    float xv = xr[k];
    float4_ wr = *(const float4_*)(W2 + k * 4);
    a += xv * wr;
  }
  for (int off = 1; off < 64; off <<= 1) {
    a.x += __shfl_xor(a.x, off); a.y += __shfl_xor(a.y, off);
    a.z += __shfl_xor(a.z, off); a.w += __shfl_xor(a.w, off);
  }
  if (lane == 0) {
    *(float4_*)(h2 + n * 4) = a;
    a2s[n] = a.x * as2[0] + a.y * as2[1] + a.z * as2[2] + a.w * as2[3];
    a2d[n] = a.x * ad2[0] + a.y * ad2[1] + a.z * ad2[2] + a.w * ad2[3];
  }
}

// ---------------- GAT layer 2 -> final output ------------------------------
__global__ __launch_bounds__(256) void k_gat2(const int* __restrict__ rs, const int* __restrict__ csr,
                                              const float* __restrict__ a2s, const float* __restrict__ a2d,
                                              const float* __restrict__ h2, const float* __restrict__ b2,
                                              float* __restrict__ out) {
  int lane = threadIdx.x & 63, wv = threadIdx.x >> 6;
  int node = blockIdx.x * 4 + wv;
  int beg = rs[node], end = rs[node + 1];
  float adv = a2d[node];
  float m = -1e30f;
  for (int i = beg + lane; i < end; i += 64) {
    float e = a2s[csr[i]] + adv;
    e = (e > 0.f) ? e : 0.2f * e;
    m = fmaxf(m, e);
  }
  for (int off = 1; off < 64; off <<= 1) m = fmaxf(m, __shfl_xor(m, off));
  float4_ acc = {0.f, 0.f, 0.f, 0.f};
  float ps = 0.f;
  for (int i = beg + lane; i < end; i += 64) {
    int s = csr[i];
    float e = a2s[s] + adv;
    e = (e > 0.f) ? e : 0.2f * e;
    float p = __expf(e - m);
    ps += p;
    float4_ hv = *(const float4_*)(h2 + (long)s * 4);
    acc += p * hv;
  }
  for (int off = 1; off < 64; off <<= 1) {
    ps += __shfl_xor(ps, off);
    acc.x += __shfl_xor(acc.x, off); acc.y += __shfl_xor(acc.y, off);
    acc.z += __shfl_xor(acc.z, off); acc.w += __shfl_xor(acc.w, off);
  }
  if (lane == 0) {
    float inv = 1.0f / (ps + 1e-16f);
    out[node * 4 + 0] = acc.x * inv + b2[0];
    out[node * 4 + 1] = acc.y * inv + b2[1];
    out[node * 4 + 2] = acc.z * inv + b2[2];
    out[node * 4 + 3] = acc.w * inv + b2[3];
  }
}

extern "C" void kernel_launch(void* const* d_in, const int* in_sizes, int n_in,
                              void* d_out, int out_size, void* d_ws, size_t ws_size,
                              hipStream_t stream) {
  (void)in_sizes; (void)n_in; (void)out_size; (void)ws_size;
  const float* text = (const float*)d_in[0];
  const float* mel  = (const float*)d_in[1];
  const int*   ei   = (const int*)d_in[2];
  const float* melW = (const float*)d_in[3];
  const float* melb = (const float*)d_in[4];
  const float* catW = (const float*)d_in[5];
  const float* catb = (const float*)d_in[6];
  const float* g1W  = (const float*)d_in[7];
  const float* g1as = (const float*)d_in[8];
  const float* g1ad = (const float*)d_in[9];
  const float* g1b  = (const float*)d_in[10];
  const float* g2W  = (const float*)d_in[11];
  const float* g2as = (const float*)d_in[12];
  const float* g2ad = (const float*)d_in[13];
  const float* g2b  = (const float*)d_in[14];
  float* out = (float*)d_out;

  char* w = (char*)d_ws;
  size_t off = 0;
  auto alloc = [&](size_t bytes) -> char* {
    char* p = w + off;
    off += (bytes + 255) & ~(size_t)255;
    return p;
  };
  _Float16* wmelF = (_Float16*)alloc((size_t)MELK * 128 * 2);
  _Float16* wcatF = (_Float16*)alloc((size_t)896 * 128 * 2);
  _Float16* w1F   = (_Float16*)alloc((size_t)128 * 256 * 2);
  float* gtmp    = (float*)alloc((size_t)4 * NN * 128 * 4);  // split-K partials
  float* melfeat = (float*)alloc((size_t)NN * 128 * 4);
  float* x1      = (float*)alloc((size_t)NN * 128 * 4);
  _Float16* h1   = (_Float16*)alloc((size_t)NN * 256 * 2);
  float* x2      = (float*)alloc((size_t)NN * 256 * 4);
  float* h2      = (float*)alloc((size_t)NN * 4 * 4);
  float* a1s     = (float*)alloc((size_t)NN * 2 * 4);
  float* a1d     = (float*)alloc((size_t)NN * 2 * 4);
  float* a2s     = (float*)alloc((size_t)NN * 4);
  float* a2d     = (float*)alloc((size_t)NN * 4);
  int* counts    = (int*)alloc((size_t)NN * 4);
  int* rs        = (int*)alloc((size_t)(NN + 1) * 4);
  int* cursor    = (int*)alloc((size_t)NN * 4);
  int* csr       = (int*)alloc((size_t)ET * 4);

  hipMemsetAsync(counts, 0, (size_t)NN * 4, stream);
  hipMemsetAsync(cursor, 0, (size_t)NN * 4, stream);

  // weight prep
  k_prep_w<<<(MELK * 128 + 255) / 256, 256, 0, stream>>>(melW, MELK, 128, wmelF);
  k_prep_w<<<(896 * 128 + 255) / 256, 256, 0, stream>>>(catW, 896, 128, wcatF);
  k_prep_w<<<(128 * 256 + 255) / 256, 256, 0, stream>>>(g1W, 128, 256, w1F);

  // CSR build
  int egrid = (ET + 255) / 256;
  k_count<<<egrid, 256, 0, stream>>>(ei, counts);
  k_scan<<<1, 1024, 0, stream>>>(counts, rs, NN);
  k_fill<<<egrid, 256, 0, stream>>>(ei, rs, cursor, csr);

  long tot128 = (long)NN * 128;
  int epigrid = (int)((tot128 / 4 + 255) / 256);

  // mel GEMM: K=6400, split-K x4 (chunks of 1600)
  k_gemm<<<dim3(157, 1, 4), 256, 0, stream>>>(mel, MELK, nullptr, 0, wmelF, MELK,
                                              1600, nullptr, 0, gtmp, 128, NN, 4, 0);
  k_epi<<<epigrid, 256, 0, stream>>>(gtmp, tot128, 4, melb, 1, melfeat, 128, tot128);

  // concat GEMM: K=896, split-K x2 (chunks of 448)
  k_gemm<<<dim3(157, 1, 2), 256, 0, stream>>>(text, TXTK, melfeat, 128, wcatF, 896,
                                              448, nullptr, 0, gtmp, 128, NN, 2, 0);
  k_epi<<<epigrid, 256, 0, stream>>>(gtmp, tot128, 2, catb, 2, x1, 128, tot128);

  // g1 GEMM: K=128, 2 col-blocks, single chunk, no act, f16 output
  k_gemm<<<dim3(157, 2, 1), 256, 0, stream>>>(x1, 128, nullptr, 0, w1F, 128,
                                              128, nullptr, 0, h1, 256, NN, 1, 1);

  // attention + aggregation
  k_att1<<<NN / 4, 256, 0, stream>>>(h1, g1as, g1ad, a1s, a1d);
  k_gat1<<<NN / 4, 256, 0, stream>>>(rs, csr, a1s, a1d, h1, g1b, x2);
  k_h2att2<<<NN / 4, 256, 0, stream>>>(x2, g2W, g2as, g2ad, h2, a2s, a2d);
  k_gat2<<<NN / 4, 256, 0, stream>>>(rs, csr, a2s, a2d, h2, g2b, out);
}